// Round 1
// baseline (392.702 us; speedup 1.0000x reference)
//
#include <hip/hip_runtime.h>
#include <stdint.h>

// TransformerBlock on MI355X (gfx950), bf16-MFMA implementation.
// Pipeline: cast(X,Wqkv,W1,W2)->bf16 | QKV gemm | V transpose | flash attn |
//           add+LN1 | FFN1 gemm(relu+bias) | FFN2 gemm(bias) | add+LN2.
// All matmuls: C = A @ B^T with A[M,K], B[N,K] bf16 row-major (weights are
// stored [out,in] so B^T form is natural). fp32 accum everywhere.

#define NTOK 2048
#define DMODEL 1024
#define NHEAD 16
#define DHEAD 64
#define DFF 4096

typedef __attribute__((ext_vector_type(8))) short short8;
typedef __attribute__((ext_vector_type(4))) short short4v;
typedef __attribute__((ext_vector_type(4))) float f32x4;

// fp32 -> bf16 RNE (no NaN handling needed for this data)
__device__ __forceinline__ short f2b(float f) {
  union { float f; unsigned u; } v; v.f = f;
  unsigned r = v.u + 0x7fffu + ((v.u >> 16) & 1u);
  return (short)(r >> 16);
}

__device__ __forceinline__ void gload_lds16(const void* g, void* l) {
  // async global->LDS, 16B/lane; LDS dest is wave-uniform base + lane*16
  __builtin_amdgcn_global_load_lds((const __attribute__((address_space(1))) void*)g,
                                   (__attribute__((address_space(3))) void*)l,
                                   16, 0, 0);
}

// ---------------- cast fp32 -> bf16, 8 elems/thread ----------------
__global__ void cast_bf16_kernel(const float* __restrict__ in, short* __restrict__ out, int n8) {
  int i = blockIdx.x * blockDim.x + threadIdx.x;
  if (i >= n8) return;
  const float4* p = (const float4*)(in + (size_t)i * 8);
  float4 a = p[0], b = p[1];
  short8 o;
  o[0] = f2b(a.x); o[1] = f2b(a.y); o[2] = f2b(a.z); o[3] = f2b(a.w);
  o[4] = f2b(b.x); o[5] = f2b(b.y); o[6] = f2b(b.z); o[7] = f2b(b.w);
  *(short8*)(out + (size_t)i * 8) = o;
}

// ---------------- GEMM: C = A @ B^T (+bias, relu), bf16 in, f32 acc ----------------
// m97-style: BMxBN tile, BK=32, waves WRxWC each computing 64x64 (4x4 frags of 16x16x32).
template<int BM, int BN, int WR, int WC, bool BF16OUT, bool BIAS, bool RELU>
__launch_bounds__(WR * WC * 64)
__global__ void gemm_bt(const short* __restrict__ A, const short* __restrict__ B,
                        const float* __restrict__ bias,
                        float* __restrict__ Cf, short* __restrict__ Cb,
                        int M, int N, int K) {
  constexpr int BK = 32;
  constexpr int THREADS = WR * WC * 64;
  constexpr int AISS = (BM * BK) / (8 * THREADS);
  constexpr int BISS = (BN * BK) / (8 * THREADS);
  __shared__ short As[BM * BK];
  __shared__ short Bs[BN * BK];
  const int t = threadIdx.x;
  const int l = t & 63;
  const int w = t >> 6;
  const int wr = w / WC, wc = w % WC;
  const int lr = l & 15, lg = l >> 4;
  const int m0 = blockIdx.y * BM, n0 = blockIdx.x * BN;
  f32x4 acc[4][4] = {};
  for (int k0 = 0; k0 < K; k0 += BK) {
#pragma unroll
    for (int i = 0; i < AISS; ++i) {
      int e = (i * THREADS + t) * 8;
      int r = e >> 5, c = e & 31;
      gload_lds16(A + (size_t)(m0 + r) * K + k0 + c, As + (size_t)(i * THREADS + w * 64) * 8);
    }
#pragma unroll
    for (int i = 0; i < BISS; ++i) {
      int e = (i * THREADS + t) * 8;
      int r = e >> 5, c = e & 31;
      gload_lds16(B + (size_t)(n0 + r) * K + k0 + c, Bs + (size_t)(i * THREADS + w * 64) * 8);
    }
    __syncthreads();  // compiler drains vmcnt before barrier
    short8 a[4], b[4];
#pragma unroll
    for (int m = 0; m < 4; ++m)
      a[m] = *(const short8*)(As + (wr * 64 + m * 16 + lr) * BK + lg * 8);
#pragma unroll
    for (int n = 0; n < 4; ++n)
      b[n] = *(const short8*)(Bs + (wc * 64 + n * 16 + lr) * BK + lg * 8);
#pragma unroll
    for (int m = 0; m < 4; ++m)
#pragma unroll
      for (int n = 0; n < 4; ++n)
        acc[m][n] = __builtin_amdgcn_mfma_f32_16x16x32_bf16(a[m], b[n], acc[m][n], 0, 0, 0);
    __syncthreads();
  }
  // epilogue: C/D layout col = lane&15, row = (lane>>4)*4 + reg
#pragma unroll
  for (int n = 0; n < 4; ++n) {
    const int col = n0 + wc * 64 + n * 16 + lr;
    const float bv = BIAS ? bias[col] : 0.0f;
#pragma unroll
    for (int m = 0; m < 4; ++m) {
#pragma unroll
      for (int r = 0; r < 4; ++r) {
        const int row = m0 + wr * 64 + m * 16 + lg * 4 + r;
        float v = acc[m][n][r] + bv;
        if (RELU) v = fmaxf(v, 0.0f);
        if (BF16OUT) Cb[(size_t)row * N + col] = f2b(v);
        else         Cf[(size_t)row * N + col] = v;
      }
    }
  }
}

// ---------------- transpose V: qkvb[:,1024:2048] ([N][D]) -> vt [D][N] ----------------
__global__ void transpose_v(const short* __restrict__ src, short* __restrict__ dst) {
  __shared__ short tile[64][65];
  const int bx = blockIdx.x * 64;  // d
  const int by = blockIdx.y * 64;  // n
  const int t = threadIdx.x;
  const int tx = t & 63, ty = t >> 6;
#pragma unroll
  for (int i = 0; i < 64; i += 4)
    tile[ty + i][tx] = src[(size_t)(by + ty + i) * 2048 + 1024 + bx + tx];
  __syncthreads();
#pragma unroll
  for (int i = 0; i < 64; i += 4)
    dst[(size_t)(bx + ty + i) * 2048 + by + tx] = tile[tx][ty + i];
}

// ---------------- flash attention (Q==K shared), bf16 MFMA, f32 softmax ----------------
// grid (N/64, H); 4 waves/block, wave w owns q rows qb*64+w*16..+16.
// K/V read straight from global (L2-resident: 256KB/head). P goes through
// wave-private LDS to convert C-frag layout -> A-frag layout.
__launch_bounds__(256)
__global__ void flash_attn(const short* __restrict__ qk, const short* __restrict__ vt,
                           float* __restrict__ O) {
  const int t = threadIdx.x, l = t & 63, w = t >> 6;
  const int lr = l & 15, lg = l >> 4;
  const int h = blockIdx.y;
  const int qb = blockIdx.x;
  __shared__ short Pl[4][16][72];  // pad 72: 144B row stride keeps 16B align, spreads banks
  const float scale = 0.125f;      // 1/sqrt(64)

  short8 aq[2];
  const int qrow = qb * 64 + w * 16 + lr;
#pragma unroll
  for (int f = 0; f < 2; ++f)
    aq[f] = *(const short8*)(qk + (size_t)qrow * 2048 + h * 64 + f * 32 + lg * 8);

  f32x4 o[4] = {};
  float mrun[4] = {-1e30f, -1e30f, -1e30f, -1e30f};
  float lrun[4] = {0.f, 0.f, 0.f, 0.f};

  for (int kt = 0; kt < NTOK / 64; ++kt) {
    f32x4 s[4] = {};
#pragma unroll
    for (int f = 0; f < 2; ++f) {
      short8 bk[4];
#pragma unroll
      for (int n = 0; n < 4; ++n)
        bk[n] = *(const short8*)(qk + (size_t)(kt * 64 + n * 16 + lr) * 2048 + h * 64 + f * 32 + lg * 8);
#pragma unroll
      for (int n = 0; n < 4; ++n)
        s[n] = __builtin_amdgcn_mfma_f32_16x16x32_bf16(aq[f], bk[n], s[n], 0, 0, 0);
    }
    // online softmax; lane holds rows lg*4+r (r=0..3), cols kt*64+n*16+lr
    float ss[4][4];
#pragma unroll
    for (int n = 0; n < 4; ++n)
#pragma unroll
      for (int r = 0; r < 4; ++r)
        ss[n][r] = s[n][r] * scale;
    float tm[4];
#pragma unroll
    for (int r = 0; r < 4; ++r)
      tm[r] = fmaxf(fmaxf(ss[0][r], ss[1][r]), fmaxf(ss[2][r], ss[3][r]));
#pragma unroll
    for (int d = 1; d < 16; d <<= 1)
#pragma unroll
      for (int r = 0; r < 4; ++r)
        tm[r] = fmaxf(tm[r], __shfl_xor(tm[r], d));
    float corr[4], psum[4];
#pragma unroll
    for (int r = 0; r < 4; ++r) {
      float mnew = fmaxf(mrun[r], tm[r]);
      corr[r] = __expf(mrun[r] - mnew);
      mrun[r] = mnew;
      psum[r] = 0.0f;
    }
    float p[4][4];
#pragma unroll
    for (int n = 0; n < 4; ++n)
#pragma unroll
      for (int r = 0; r < 4; ++r) {
        p[n][r] = __expf(ss[n][r] - mrun[r]);
        psum[r] += p[n][r];
      }
#pragma unroll
    for (int d = 1; d < 16; d <<= 1)
#pragma unroll
      for (int r = 0; r < 4; ++r)
        psum[r] += __shfl_xor(psum[r], d);
#pragma unroll
    for (int r = 0; r < 4; ++r)
      lrun[r] = lrun[r] * corr[r] + psum[r];
#pragma unroll
    for (int n = 0; n < 4; ++n)
#pragma unroll
      for (int r = 0; r < 4; ++r)
        o[n][r] *= corr[r];
    // P (C-frag) -> LDS -> A-frag
#pragma unroll
    for (int n = 0; n < 4; ++n)
#pragma unroll
      for (int r = 0; r < 4; ++r)
        Pl[w][lg * 4 + r][n * 16 + lr] = f2b(p[n][r]);
    __syncthreads();
#pragma unroll
    for (int f = 0; f < 2; ++f) {
      short8 ap = *(const short8*)(&Pl[w][lr][f * 32 + lg * 8]);
      short8 bv[4];
#pragma unroll
      for (int n = 0; n < 4; ++n)
        bv[n] = *(const short8*)(vt + (size_t)(h * 64 + n * 16 + lr) * 2048 + kt * 64 + f * 32 + lg * 8);
#pragma unroll
      for (int n = 0; n < 4; ++n)
        o[n] = __builtin_amdgcn_mfma_f32_16x16x32_bf16(ap, bv[n], o[n], 0, 0, 0);
    }
    __syncthreads();
  }
#pragma unroll
  for (int n = 0; n < 4; ++n)
#pragma unroll
    for (int r = 0; r < 4; ++r)
      O[(size_t)(qb * 64 + w * 16 + lg * 4 + r) * 1024 + h * 64 + n * 16 + lr] = o[n][r] / lrun[r];
}

// ---------------- out = LN(A + B) * g + be ; optional bf16 copy ----------------
__launch_bounds__(256)
__global__ void add_ln(const float* __restrict__ A, const float* __restrict__ B,
                       const float* __restrict__ g, const float* __restrict__ be,
                       float* __restrict__ outf, short* __restrict__ outb) {
  const int row = blockIdx.x;
  const int t = threadIdx.x;
  const size_t base = (size_t)row * 1024 + t * 4;
  float4 a = *(const float4*)(A + base);
  float4 b = *(const float4*)(B + base);
  float4 s; s.x = a.x + b.x; s.y = a.y + b.y; s.z = a.z + b.z; s.w = a.w + b.w;
  float sum = s.x + s.y + s.z + s.w;
  float sq  = s.x * s.x + s.y * s.y + s.z * s.z + s.w * s.w;
#pragma unroll
  for (int d = 32; d > 0; d >>= 1) {
    sum += __shfl_down(sum, d);
    sq  += __shfl_down(sq, d);
  }
  __shared__ float red[8];
  const int w = t >> 6, l = t & 63;
  if (l == 0) { red[w] = sum; red[4 + w] = sq; }
  __syncthreads();
  sum = red[0] + red[1] + red[2] + red[3];
  sq  = red[4] + red[5] + red[6] + red[7];
  const float mu = sum * (1.0f / 1024.0f);
  const float rstd = rsqrtf(sq * (1.0f / 1024.0f) - mu * mu + 1e-5f);
  float4 gv = *(const float4*)(g + t * 4);
  float4 bv = *(const float4*)(be + t * 4);
  float4 o;
  o.x = (s.x - mu) * rstd * gv.x + bv.x;
  o.y = (s.y - mu) * rstd * gv.y + bv.y;
  o.z = (s.z - mu) * rstd * gv.z + bv.z;
  o.w = (s.w - mu) * rstd * gv.w + bv.w;
  *(float4*)(outf + base) = o;
  if (outb) {
    short4v ob; ob.x = f2b(o.x); ob.y = f2b(o.y); ob.z = f2b(o.z); ob.w = f2b(o.w);
    *(short4v*)(outb + base) = ob;
  }
}

extern "C" void kernel_launch(void* const* d_in, const int* in_sizes, int n_in,
                              void* d_out, int out_size, void* d_ws, size_t ws_size,
                              hipStream_t stream) {
  const float* X    = (const float*)d_in[0];
  const float* Wqkv = (const float*)d_in[1];
  const float* W1   = (const float*)d_in[2];
  const float* b1   = (const float*)d_in[3];
  const float* W2   = (const float*)d_in[4];
  const float* b2   = (const float*)d_in[5];
  const float* g1   = (const float*)d_in[6];
  const float* be1  = (const float*)d_in[7];
  const float* g2   = (const float*)d_in[8];
  const float* be2  = (const float*)d_in[9];

  // workspace layout (68 MiB total, 256B aligned)
  char* p = (char*)d_ws;
  auto alloc = [&](size_t bytes) { char* r = p; p += (bytes + 255) & ~(size_t)255; return r; };
  short* Xb    = (short*)alloc((size_t)NTOK * DMODEL * 2);        // 4M  (reused as hb)
  short* Wqkvb = (short*)alloc((size_t)2 * DMODEL * DMODEL * 2);  // 4M
  short* W1b   = (short*)alloc((size_t)DFF * DMODEL * 2);         // 8M
  short* W2b   = (short*)alloc((size_t)DMODEL * DFF * 2);         // 8M
  short* qkvb  = (short*)alloc((size_t)NTOK * 2 * DMODEL * 2);    // 8M  (reused as ffn2 f32)
  short* vt    = (short*)alloc((size_t)DMODEL * NTOK * 2);        // 4M
  float* attn  = (float*)alloc((size_t)NTOK * DMODEL * 4);        // 8M
  float* h     = (float*)alloc((size_t)NTOK * DMODEL * 4);        // 8M
  short* y1b   = (short*)alloc((size_t)NTOK * DFF * 2);           // 16M
  float* ffn2  = (float*)qkvb;  // qkvb dead after attention
  short* hb    = Xb;            // Xb dead after QKV gemm

  cast_bf16_kernel<<<(NTOK * DMODEL / 8 + 255) / 256, 256, 0, stream>>>(X, Xb, NTOK * DMODEL / 8);
  cast_bf16_kernel<<<(2 * DMODEL * DMODEL / 8 + 255) / 256, 256, 0, stream>>>(Wqkv, Wqkvb, 2 * DMODEL * DMODEL / 8);
  cast_bf16_kernel<<<(DFF * DMODEL / 8 + 255) / 256, 256, 0, stream>>>(W1, W1b, DFF * DMODEL / 8);
  cast_bf16_kernel<<<(DMODEL * DFF / 8 + 255) / 256, 256, 0, stream>>>(W2, W2b, DMODEL * DFF / 8);

  {  // qkv = X @ Wqkv^T  -> bf16 [2048, 2048]
    dim3 grid(2 * DMODEL / 128, NTOK / 128);
    gemm_bt<128, 128, 2, 2, true, false, false><<<grid, 256, 0, stream>>>(
        Xb, Wqkvb, nullptr, nullptr, qkvb, NTOK, 2 * DMODEL, DMODEL);
  }
  {  // vt[d][n] = v[n][d]
    dim3 grid(DMODEL / 64, NTOK / 64);
    transpose_v<<<grid, 256, 0, stream>>>(qkvb, vt);
  }
  {  // attn_out f32 [2048, 1024]
    dim3 grid(NTOK / 64, NHEAD);
    flash_attn<<<grid, 256, 0, stream>>>(qkvb, vt, attn);
  }
  add_ln<<<NTOK, 256, 0, stream>>>(X, attn, g1, be1, h, hb);
  {  // y1 = relu(h @ W1^T + b1) -> bf16 [2048, 4096]
    dim3 grid(DFF / 128, NTOK / 128);
    gemm_bt<128, 128, 2, 2, true, true, true><<<grid, 256, 0, stream>>>(
        hb, W1b, b1, nullptr, y1b, NTOK, DFF, DMODEL);
  }
  {  // ffn2 = y1 @ W2^T + b2 -> f32 [2048, 1024]; BM=64 so grid=256 wgs (full CU coverage)
    dim3 grid(DMODEL / 128, NTOK / 64);
    gemm_bt<64, 128, 1, 2, false, true, false><<<grid, 128, 0, stream>>>(
        y1b, W2b, b2, ffn2, nullptr, NTOK, DMODEL, DFF);
  }
  add_ln<<<NTOK, 256, 0, stream>>>(h, ffn2, g2, be2, (float*)d_out, nullptr);
}

// Round 4
// 343.829 us; speedup vs baseline: 1.1421x; 1.1421x over previous
//
#include <hip/hip_runtime.h>
#include <stdint.h>

// TransformerBlock on MI355X (gfx950), bf16-MFMA implementation. Round 4.
// = Round-2 kernel with one fix: __exp2f (absent in this ROCm's headers; glibc
// macro collision) replaced by __builtin_amdgcn_exp2f (v_exp_f32 = 2^x).

#define NTOK 2048
#define DMODEL 1024
#define NHEAD 16
#define DHEAD 64
#define DFF 4096

typedef __attribute__((ext_vector_type(8))) short short8;
typedef __attribute__((ext_vector_type(4))) short short4v;
typedef __attribute__((ext_vector_type(4))) float f32x4;

__device__ __forceinline__ float fexp2(float x) { return __builtin_amdgcn_exp2f(x); }

// fp32 -> bf16 RNE
__device__ __forceinline__ short f2b(float f) {
  union { float f; unsigned u; } v; v.f = f;
  unsigned r = v.u + 0x7fffu + ((v.u >> 16) & 1u);
  return (short)(r >> 16);
}

__device__ __forceinline__ void gload_lds16(const void* g, void* l) {
  __builtin_amdgcn_global_load_lds((const __attribute__((address_space(1))) void*)g,
                                   (__attribute__((address_space(3))) void*)l,
                                   16, 0, 0);
}

// ---------------- fused cast fp32 -> bf16 for 4 tensors, 8 elems/thread ----------------
__global__ void cast_all(const float* __restrict__ s0, short* __restrict__ d0, int n0,
                         const float* __restrict__ s1, short* __restrict__ d1, int n1,
                         const float* __restrict__ s2, short* __restrict__ d2, int n2,
                         const float* __restrict__ s3, short* __restrict__ d3, int n3) {
  int i = blockIdx.x * blockDim.x + threadIdx.x;
  const float* s; short* d; int j = i;
  if (j < n0) { s = s0; d = d0; }
  else { j -= n0;
    if (j < n1) { s = s1; d = d1; }
    else { j -= n1;
      if (j < n2) { s = s2; d = d2; }
      else { j -= n2; if (j >= n3) return; s = s3; d = d3; }
    }
  }
  const float4* p = (const float4*)(s + (size_t)j * 8);
  float4 a = p[0], b = p[1];
  short8 o;
  o[0] = f2b(a.x); o[1] = f2b(a.y); o[2] = f2b(a.z); o[3] = f2b(a.w);
  o[4] = f2b(b.x); o[5] = f2b(b.y); o[6] = f2b(b.z); o[7] = f2b(b.w);
  *(short8*)(d + (size_t)j * 8) = o;
}

// ---------------- GEMM: C = A @ B^T (+relu/bias), bf16 in, f32 acc ----------------
// m97-style. Supports split-K via blockIdx.z (koff = z*kstep, Cf += z*M*N).
template<int BM, int BN, int WR, int WC, bool BF16OUT, bool BIAS, bool RELU>
__launch_bounds__(WR * WC * 64)
__global__ void gemm_bt(const short* __restrict__ A, const short* __restrict__ B,
                        const float* __restrict__ bias,
                        float* __restrict__ Cf, short* __restrict__ Cb,
                        int M, int N, int K, int lda, int ldb, int kstep) {
  constexpr int BK = 32;
  constexpr int THREADS = WR * WC * 64;
  constexpr int AISS = (BM * BK) / (8 * THREADS);
  constexpr int BISS = (BN * BK) / (8 * THREADS);
  __shared__ short As[BM * BK];
  __shared__ short Bs[BN * BK];
  const int t = threadIdx.x;
  const int l = t & 63;
  const int w = t >> 6;
  const int wr = w / WC, wc = w % WC;
  const int lr = l & 15, lg = l >> 4;
  const int m0 = blockIdx.y * BM, n0 = blockIdx.x * BN;
  const int koff = blockIdx.z * kstep;
  A += koff; B += koff;
  Cf += (size_t)blockIdx.z * M * N;
  f32x4 acc[4][4] = {};
  for (int k0 = 0; k0 < K; k0 += BK) {
#pragma unroll
    for (int i = 0; i < AISS; ++i) {
      int e = (i * THREADS + t) * 8;
      int r = e >> 5, c = e & 31;
      gload_lds16(A + (size_t)(m0 + r) * lda + k0 + c, As + (size_t)(i * THREADS + w * 64) * 8);
    }
#pragma unroll
    for (int i = 0; i < BISS; ++i) {
      int e = (i * THREADS + t) * 8;
      int r = e >> 5, c = e & 31;
      gload_lds16(B + (size_t)(n0 + r) * ldb + k0 + c, Bs + (size_t)(i * THREADS + w * 64) * 8);
    }
    __syncthreads();
    short8 a[4], b[4];
#pragma unroll
    for (int m = 0; m < 4; ++m)
      a[m] = *(const short8*)(As + (wr * 64 + m * 16 + lr) * BK + lg * 8);
#pragma unroll
    for (int n = 0; n < 4; ++n)
      b[n] = *(const short8*)(Bs + (wc * 64 + n * 16 + lr) * BK + lg * 8);
#pragma unroll
    for (int m = 0; m < 4; ++m)
#pragma unroll
      for (int n = 0; n < 4; ++n)
        acc[m][n] = __builtin_amdgcn_mfma_f32_16x16x32_bf16(a[m], b[n], acc[m][n], 0, 0, 0);
    __syncthreads();
  }
#pragma unroll
  for (int n = 0; n < 4; ++n) {
    const int col = n0 + wc * 64 + n * 16 + lr;
    const float bv = BIAS ? bias[col] : 0.0f;
#pragma unroll
    for (int m = 0; m < 4; ++m) {
#pragma unroll
      for (int r = 0; r < 4; ++r) {
        const int row = m0 + wr * 64 + m * 16 + lg * 4 + r;
        float v = acc[m][n][r] + bv;
        if (RELU) v = fmaxf(v, 0.0f);
        if (BF16OUT) Cb[(size_t)row * N + col] = f2b(v);
        else         Cf[(size_t)row * N + col] = v;
      }
    }
  }
}

// ---------------- transpose V: qkvb[:,1024:2048] ([N][D]) -> vt [D][N] ----------------
__global__ void transpose_v(const short* __restrict__ src, short* __restrict__ dst) {
  __shared__ short tile[64][65];
  const int bx = blockIdx.x * 64;  // d
  const int by = blockIdx.y * 64;  // n
  const int t = threadIdx.x;
  const int tx = t & 63, ty = t >> 6;
#pragma unroll
  for (int i = 0; i < 64; i += 4)
    tile[ty + i][tx] = src[(size_t)(by + ty + i) * 2048 + 1024 + bx + tx];
  __syncthreads();
#pragma unroll
  for (int i = 0; i < 64; i += 4)
    dst[(size_t)(bx + ty + i) * 2048 + by + tx] = tile[tx][ty + i];
}

// ---------------- flash attention (Q==K shared), 1 wave/block, swapped QK^T ----------------
// grid (N/16, H); block = 64 threads. Lane layout after s = mfma(K,Q):
//   lane holds Q-row lr = l&15 (fixed), K-positions n*16 + lg*4 + r (16 scores).
// Softmax is per-lane over 16 values + 2 shfl_xor (lanes l, l^16, l^32, l^48 share a row).
// P -> wave-private LDS -> A-frag (no barriers; compiler lgkmcnt orders same-wave LDS).
// Pipeline: QK mfma (K preloaded) | issue V loads | issue next-K loads | softmax | PV.
__launch_bounds__(64)
__global__ void flash_attn(const short* __restrict__ qk, const short* __restrict__ vt,
                           float* __restrict__ O) {
  const int l = threadIdx.x & 63;
  const int lr = l & 15, lg = l >> 4;
  const int h = blockIdx.y;
  const int qb = blockIdx.x;  // 16 Q-rows per block
  __shared__ short Pl[16][72];  // 144B row stride: 16B-aligned b128 reads
  const float C2 = 0.18033688011112042f;  // (1/sqrt(64)) * log2(e)

  const short* kbase = qk + h * 64;
  const short* vbase = vt + (size_t)h * 64 * 2048;

  short8 aq[2];
  const int qrow = qb * 16 + lr;
#pragma unroll
  for (int f = 0; f < 2; ++f)
    aq[f] = *(const short8*)(qk + (size_t)qrow * 2048 + h * 64 + f * 32 + lg * 8);

  f32x4 o[4] = {};
  float mrun = -1e30f, lrun = 0.0f;

  short8 kA[2][4], kB[2][4];
#pragma unroll
  for (int f = 0; f < 2; ++f)
#pragma unroll
    for (int n = 0; n < 4; ++n)
      kA[f][n] = *(const short8*)(kbase + (size_t)(n * 16 + lr) * 2048 + f * 32 + lg * 8);

  auto step = [&](int kt, short8 (&kc)[2][4], short8 (&kn)[2][4], bool pref) {
    // QK^T (swapped): s[n] lane holds Q-row lr, K-pos n*16+lg*4+r
    f32x4 s[4] = {};
#pragma unroll
    for (int f = 0; f < 2; ++f)
#pragma unroll
      for (int n = 0; n < 4; ++n)
        s[n] = __builtin_amdgcn_mfma_f32_16x16x32_bf16(kc[f][n], aq[f], s[n], 0, 0, 0);
    // issue V loads (needed at end of this iter)
    short8 bv[2][4];
#pragma unroll
    for (int f = 0; f < 2; ++f)
#pragma unroll
      for (int n = 0; n < 4; ++n)
        bv[f][n] = *(const short8*)(vbase + (size_t)(n * 16 + lr) * 2048 + kt * 64 + f * 32 + lg * 8);
    // issue next K loads (after V so PV's wait keeps these in flight)
    if (pref) {
#pragma unroll
      for (int f = 0; f < 2; ++f)
#pragma unroll
        for (int n = 0; n < 4; ++n)
          kn[f][n] = *(const short8*)(kbase + (size_t)((kt + 1) * 64 + n * 16 + lr) * 2048 + f * 32 + lg * 8);
    }
    // row max: 15 in-reg + 2 shfl
    float tm = s[0][0];
#pragma unroll
    for (int n = 0; n < 4; ++n)
#pragma unroll
      for (int r = 0; r < 4; ++r)
        tm = fmaxf(tm, s[n][r]);
    tm = fmaxf(tm, __shfl_xor(tm, 16));
    tm = fmaxf(tm, __shfl_xor(tm, 32));
    const float mnew = fmaxf(mrun, tm);
    const float corr = fexp2((mrun - mnew) * C2);
    mrun = mnew;
    // p = exp2((s - m)*C2); row sum
    float p[4][4];
    float ps = 0.0f;
#pragma unroll
    for (int n = 0; n < 4; ++n)
#pragma unroll
      for (int r = 0; r < 4; ++r) {
        p[n][r] = fexp2((s[n][r] - mnew) * C2);
        ps += p[n][r];
      }
    ps += __shfl_xor(ps, 16);
    ps += __shfl_xor(ps, 32);
    lrun = lrun * corr + ps;
    // redistribute corr from P-layout (row = lr) to O-layout (rows lg*4+r)
    f32x4 cov;
#pragma unroll
    for (int r = 0; r < 4; ++r)
      cov[r] = __shfl(corr, lg * 4 + r);
#pragma unroll
    for (int n = 0; n < 4; ++n)
      o[n] *= cov;
    // P -> LDS (row lr, positions n*16+lg*4..+3), bf16 packed b64 writes
#pragma unroll
    for (int n = 0; n < 4; ++n) {
      uint2 wv;
      wv.x = ((unsigned)(unsigned short)f2b(p[n][1]) << 16) | (unsigned short)f2b(p[n][0]);
      wv.y = ((unsigned)(unsigned short)f2b(p[n][3]) << 16) | (unsigned short)f2b(p[n][2]);
      *(uint2*)&Pl[lr][n * 16 + lg * 4] = wv;
    }
    // A-frag read + PV
#pragma unroll
    for (int f = 0; f < 2; ++f) {
      short8 ap = *(const short8*)&Pl[lr][f * 32 + lg * 8];
#pragma unroll
      for (int n = 0; n < 4; ++n)
        o[n] = __builtin_amdgcn_mfma_f32_16x16x32_bf16(ap, bv[f][n], o[n], 0, 0, 0);
    }
  };

#pragma unroll 1
  for (int kt = 0; kt < 32; kt += 2) {
    step(kt, kA, kB, true);
    step(kt + 1, kB, kA, kt + 2 < 32);
  }

  // final: lrun lives per-lane for row lr; redistribute to O-layout rows lg*4+r
  f32x4 inv;
#pragma unroll
  for (int r = 0; r < 4; ++r)
    inv[r] = 1.0f / __shfl(lrun, lg * 4 + r);
#pragma unroll
  for (int n = 0; n < 4; ++n)
#pragma unroll
    for (int r = 0; r < 4; ++r)
      O[(size_t)(qb * 16 + lg * 4 + r) * 1024 + h * 64 + n * 16 + lr] = o[n][r] * inv[r];
}

// ---------------- out = LN(A + B0 [+ B1] [+ bias]) * g + be ; optional bf16 copy ----------------
__launch_bounds__(256)
__global__ void add_ln(const float* __restrict__ A, const float* __restrict__ B0,
                       const float* __restrict__ B1, const float* __restrict__ bias,
                       const float* __restrict__ g, const float* __restrict__ be,
                       float* __restrict__ outf, short* __restrict__ outb) {
  const int row = blockIdx.x;
  const int t = threadIdx.x;
  const size_t base = (size_t)row * 1024 + t * 4;
  float4 a = *(const float4*)(A + base);
  float4 b = *(const float4*)(B0 + base);
  float4 s; s.x = a.x + b.x; s.y = a.y + b.y; s.z = a.z + b.z; s.w = a.w + b.w;
  if (B1) {
    float4 c = *(const float4*)(B1 + base);
    s.x += c.x; s.y += c.y; s.z += c.z; s.w += c.w;
  }
  if (bias) {
    float4 c = *(const float4*)(bias + t * 4);
    s.x += c.x; s.y += c.y; s.z += c.z; s.w += c.w;
  }
  float sum = s.x + s.y + s.z + s.w;
  float sq  = s.x * s.x + s.y * s.y + s.z * s.z + s.w * s.w;
#pragma unroll
  for (int d = 32; d > 0; d >>= 1) {
    sum += __shfl_down(sum, d);
    sq  += __shfl_down(sq, d);
  }
  __shared__ float red[8];
  const int w = t >> 6, l = t & 63;
  if (l == 0) { red[w] = sum; red[4 + w] = sq; }
  __syncthreads();
  sum = red[0] + red[1] + red[2] + red[3];
  sq  = red[4] + red[5] + red[6] + red[7];
  const float mu = sum * (1.0f / 1024.0f);
  const float rstd = rsqrtf(sq * (1.0f / 1024.0f) - mu * mu + 1e-5f);
  float4 gv = *(const float4*)(g + t * 4);
  float4 bv = *(const float4*)(be + t * 4);
  float4 o;
  o.x = (s.x - mu) * rstd * gv.x + bv.x;
  o.y = (s.y - mu) * rstd * gv.y + bv.y;
  o.z = (s.z - mu) * rstd * gv.z + bv.z;
  o.w = (s.w - mu) * rstd * gv.w + bv.w;
  *(float4*)(outf + base) = o;
  if (outb) {
    short4v ob; ob.x = f2b(o.x); ob.y = f2b(o.y); ob.z = f2b(o.z); ob.w = f2b(o.w);
    *(short4v*)(outb + base) = ob;
  }
}

extern "C" void kernel_launch(void* const* d_in, const int* in_sizes, int n_in,
                              void* d_out, int out_size, void* d_ws, size_t ws_size,
                              hipStream_t stream) {
  const float* X    = (const float*)d_in[0];
  const float* Wqkv = (const float*)d_in[1];
  const float* W1   = (const float*)d_in[2];
  const float* b1   = (const float*)d_in[3];
  const float* W2   = (const float*)d_in[4];
  const float* b2   = (const float*)d_in[5];
  const float* g1   = (const float*)d_in[6];
  const float* be1  = (const float*)d_in[7];
  const float* g2   = (const float*)d_in[8];
  const float* be2  = (const float*)d_in[9];

  // workspace layout (68 MiB)
  char* p = (char*)d_ws;
  auto alloc = [&](size_t bytes) { char* r = p; p += (bytes + 255) & ~(size_t)255; return r; };
  short* Xb    = (short*)alloc((size_t)NTOK * DMODEL * 2);        // 4M  (reused as hb)
  short* Wqkvb = (short*)alloc((size_t)2 * DMODEL * DMODEL * 2);  // 4M
  short* W1b   = (short*)alloc((size_t)DFF * DMODEL * 2);         // 8M
  short* W2b   = (short*)alloc((size_t)DMODEL * DFF * 2);         // 8M
  short* qkvb  = (short*)alloc((size_t)NTOK * 2 * DMODEL * 2);    // 8M  (later: FFN2 partial 0)
  short* vt    = (short*)alloc((size_t)DMODEL * NTOK * 2);        // 4M  (later: FFN2 partial 1, spills into attn)
  float* attn  = (float*)alloc((size_t)NTOK * DMODEL * 4);        // 8M
  float* h     = (float*)alloc((size_t)NTOK * DMODEL * 4);        // 8M
  short* y1b   = (short*)alloc((size_t)NTOK * DFF * 2);           // 16M
  short* hb    = Xb;  // Xb dead after QKV gemm
  float* P0    = (float*)qkvb;                // 8M  (qkvb dead after attention)
  float* P1    = P0 + (size_t)NTOK * DMODEL;  // 8M  (vt + first half of attn, dead after LN1)

  cast_all<<<6144, 256, 0, stream>>>(X, Xb, NTOK * DMODEL / 8,
                                     Wqkv, Wqkvb, 2 * DMODEL * DMODEL / 8,
                                     W1, W1b, DFF * DMODEL / 8,
                                     W2, W2b, DMODEL * DFF / 8);

  {  // qkv = X @ Wqkv^T -> bf16 [2048, 2048]
    dim3 grid(2 * DMODEL / 128, NTOK / 128, 1);
    gemm_bt<128, 128, 2, 2, true, false, false><<<grid, 256, 0, stream>>>(
        Xb, Wqkvb, nullptr, nullptr, qkvb, NTOK, 2 * DMODEL, DMODEL, DMODEL, DMODEL, 0);
  }
  {  // vt[d][n] = v[n][d]
    dim3 grid(DMODEL / 64, NTOK / 64);
    transpose_v<<<grid, 256, 0, stream>>>(qkvb, vt);
  }
  {  // attn_out f32 [2048, 1024]; 1 wave/block, 16 Q-rows each
    dim3 grid(NTOK / 16, NHEAD);
    flash_attn<<<grid, 64, 0, stream>>>(qkvb, vt, attn);
  }
  add_ln<<<NTOK, 256, 0, stream>>>(X, attn, nullptr, nullptr, g1, be1, h, hb);
  {  // y1 = relu(h @ W1^T + b1) -> bf16 [2048, 4096]
    dim3 grid(DFF / 128, NTOK / 128, 1);
    gemm_bt<128, 128, 2, 2, true, true, true><<<grid, 256, 0, stream>>>(
        hb, W1b, b1, nullptr, y1b, NTOK, DFF, DMODEL, DMODEL, DMODEL, 0);
  }
  {  // ffn2 partials: split-K=2, K=2048 each, lda/ldb=4096; bias b2 folded into LN2
    dim3 grid(DMODEL / 128, NTOK / 128, 2);
    gemm_bt<128, 128, 2, 2, false, false, false><<<grid, 256, 0, stream>>>(
        y1b, W2b, nullptr, P0, nullptr, NTOK, DMODEL, 2048, DFF, DFF, 2048);
  }
  add_ln<<<NTOK, 256, 0, stream>>>(h, P0, P1, b2, g2, be2, (float*)d_out, nullptr);
}